// Round 11
// baseline (1190.809 us; speedup 1.0000x reference)
//
#include <hip/hip_runtime.h>

#define N_NODES 100000
#define N_EDGES 1600000
#define D_FEAT  48

#define BKT_SHIFT 9                                   // 512 nodes per coarse bucket
#define BKT_NODES (1 << BKT_SHIFT)
#define NBKT ((N_NODES + BKT_NODES - 1) / BKT_NODES)  // 196
#define EPB1 2048                                     // edges per phase-1 block
#define NB1  ((N_EDGES + EPB1 - 1) / EPB1)            // 782
#define P2_CAP 9216                                   // LDS-staged edges (avg 8192)
#define TILE_SHIFT 14                                 // src tile = src>>14 (0..6)
#define NTILE 8
#define KEYS (BKT_NODES * NTILE)                      // 4096
#define ACC_STRIDE 49                                 // 48+1: gcd(49,32)=1 -> no bank alias

__device__ __forceinline__ unsigned short bf16_rn(float f) {
    unsigned u = __float_as_uint(f);
    unsigned r = (u + 0x7fffu + ((u >> 16) & 1u)) >> 16;
    return (unsigned short)r;
}
__device__ __forceinline__ float bf2f(unsigned short b) {
    return __uint_as_float(((unsigned)b) << 16);
}

// ---------- fused: x(f32)->xb(bf16)  +  coarse histogram ----------
__global__ void cvt_hist_kernel(const float* __restrict__ in,
                                unsigned short* __restrict__ outb,
                                const int* __restrict__ dst,
                                int* __restrict__ ccount) {
    __shared__ int cnt[NBKT];
    for (int i = threadIdx.x; i < NBKT; i += blockDim.x) cnt[i] = 0;
    __syncthreads();
    int tid = blockIdx.x * blockDim.x + threadIdx.x;
    int stride = gridDim.x * blockDim.x;
    const float4* in4 = (const float4*)in;
    ushort4* o4 = (ushort4*)outb;
    const int n4 = (N_NODES * D_FEAT) / 4;
    for (int i = tid; i < n4; i += stride) {
        float4 v = in4[i];
        ushort4 o;
        o.x = bf16_rn(v.x); o.y = bf16_rn(v.y);
        o.z = bf16_rn(v.z); o.w = bf16_rn(v.w);
        o4[i] = o;
    }
    for (int e = tid; e < N_EDGES; e += stride)
        atomicAdd(&cnt[dst[e] >> BKT_SHIFT], 1);
    __syncthreads();
    for (int i = threadIdx.x; i < NBKT; i += blockDim.x)
        if (cnt[i]) atomicAdd(&ccount[i], cnt[i]);
}

__global__ void scan196_kernel(const int* __restrict__ ccount,
                               int* __restrict__ bbase,
                               int* __restrict__ cursor) {
    __shared__ int sdata[256];
    int t = threadIdx.x;
    int v = (t < NBKT) ? ccount[t] : 0;
    sdata[t] = v;
    __syncthreads();
    for (int off = 1; off < 256; off <<= 1) {
        int u = (t >= off) ? sdata[t - off] : 0;
        __syncthreads();
        sdata[t] += u;
        __syncthreads();
    }
    if (t < NBKT) { int ex = sdata[t] - v; bbase[t] = ex; cursor[t] = ex; }
    if (t == 0)   { bbase[NBKT] = N_EDGES; }
}

// coarse.x = dst_local(9b) | src<<9 ; coarse.y = w bits.
__global__ void p1_kernel(const float* __restrict__ w,
                          const int*   __restrict__ src,
                          const int*   __restrict__ dst,
                          int*         __restrict__ cursor,
                          uint2*       __restrict__ coarse) {
    __shared__ uint2 stage[EPB1];
    __shared__ unsigned char sbkt[EPB1];
    __shared__ int cnt[NBKT], base[NBKT];
    for (int i = threadIdx.x; i < NBKT; i += blockDim.x) cnt[i] = 0;
    __syncthreads();
    int e0 = blockIdx.x * EPB1;
    int n = N_EDGES - e0; if (n > EPB1) n = EPB1;
    for (int i = threadIdx.x; i < n; i += blockDim.x) {
        int e = e0 + i;
        int d = dst[e];
        int b = d >> BKT_SHIFT;
        atomicAdd(&cnt[b], 1);
        stage[i] = make_uint2((unsigned)(d & (BKT_NODES - 1)) | ((unsigned)src[e] << BKT_SHIFT),
                              (unsigned)__float_as_uint(w[e]));
        sbkt[i] = (unsigned char)b;
    }
    __syncthreads();
    for (int i = threadIdx.x; i < NBKT; i += blockDim.x) {
        int c = cnt[i];
        base[i] = c ? atomicAdd(&cursor[i], c) : 0;
        cnt[i] = 0;  // reuse as local cursor
    }
    __syncthreads();
    for (int i = threadIdx.x; i < n; i += blockDim.x) {
        int b = sbkt[i];
        int pos = base[b] + atomicAdd(&cnt[b], 1);
        coarse[pos] = stage[i];
    }
}

// Phase 2: one block per coarse bucket. Key = TILE-MAJOR (tile<<9 | dst_local)
// so the SpMM block sweeps x in src-tile phase. recs.x = dst_local<<17 | src.
__global__ __launch_bounds__(512) void p2_kernel(const uint2* __restrict__ coarse,
                                                 const int*   __restrict__ bbase,
                                                 uint2*       __restrict__ recs) {
    __shared__ uint2 sedge[P2_CAP];     // 72 KB
    __shared__ int cnt[KEYS];           // 16 KB
    __shared__ int ssum[512];           // 2 KB
    int b = blockIdx.x, t = threadIdx.x;
    int lo = bbase[b], hi = bbase[b + 1];
    int m = hi - lo;
    int staged = (m < P2_CAP) ? m : P2_CAP;
    for (int i = t; i < staged; i += 512) sedge[i] = coarse[lo + i];
    for (int k = t; k < KEYS; k += 512) cnt[k] = 0;
    __syncthreads();
    for (int i = t; i < m; i += 512) {
        uint2 r = (i < staged) ? sedge[i] : coarse[lo + i];
        unsigned src = r.x >> BKT_SHIFT;
        unsigned key = ((src >> TILE_SHIFT) << BKT_SHIFT) | (r.x & (BKT_NODES - 1));
        atomicAdd(&cnt[key], 1);
    }
    __syncthreads();
    int base = t << 3;                   // thread t owns keys [8t, 8t+8)
    int local[8];
    int s = 0;
#pragma unroll
    for (int j = 0; j < 8; ++j) { local[j] = s; s += cnt[base + j]; }
    ssum[t] = s;
    __syncthreads();
    for (int off = 1; off < 512; off <<= 1) {
        int u = (t >= off) ? ssum[t - off] : 0;
        __syncthreads();
        ssum[t] += u;
        __syncthreads();
    }
    int pre = lo + ssum[t] - s;
#pragma unroll
    for (int j = 0; j < 8; ++j) cnt[base + j] = pre + local[j];
    __syncthreads();
    for (int i = t; i < m; i += 512) {
        uint2 r = (i < staged) ? sedge[i] : coarse[lo + i];
        unsigned src = r.x >> BKT_SHIFT;
        unsigned dl  = r.x & (BKT_NODES - 1);
        unsigned key = ((src >> TILE_SHIFT) << BKT_SHIFT) | dl;
        int pos = atomicAdd(&cnt[key], 1);
        recs[pos] = make_uint2((dl << 17) | src, r.y);
    }
}

// ---------- SpMM: edge-parallel, LDS f32 accumulation (no divergence) ----------
// One block per bucket. 4 lanes/edge; lane q owns float4 slots {q, 4+q, 8+q}.
template <bool OUT_BF16>
__global__ __launch_bounds__(512) void spmm_lds_kernel(const unsigned short* __restrict__ xb,
                                                       const uint2* __restrict__ recs,
                                                       const int*   __restrict__ bbase,
                                                       void* __restrict__ outv) {
    __shared__ float acc[BKT_NODES * ACC_STRIDE];   // 100,352 B
    int b = blockIdx.x, t = threadIdx.x;
    for (int i = t; i < BKT_NODES * ACC_STRIDE; i += 512) acc[i] = 0.f;
    __syncthreads();
    int lo = bbase[b], hi = bbase[b + 1];
    int g = t >> 2, q = t & 3;
    // stride-2 group permute: consecutive edges (often same dst after the
    // (tile,dst) sort) land in different wave-instrs -> no same-addr LDS serialization
    int eg = ((g & 63) << 1) | (g >> 6);
    const ushort4* __restrict__ X = reinterpret_cast<const ushort4*>(xb);
    int f0 = q << 2;
    for (int e = lo + eg; e < hi; e += 128) {
        uint2 r = recs[e];
        int src = (int)(r.x & 0x1FFFFu);
        int dl  = (int)(r.x >> 17);
        float w = __uint_as_float(r.y);
        const ushort4* xr = X + (size_t)src * (D_FEAT / 4);
        ushort4 u0 = xr[q], u1 = xr[4 + q], u2 = xr[8 + q];
        float* arow = acc + dl * ACC_STRIDE;
        atomicAdd(&arow[f0 + 0],      w * bf2f(u0.x));
        atomicAdd(&arow[f0 + 1],      w * bf2f(u0.y));
        atomicAdd(&arow[f0 + 2],      w * bf2f(u0.z));
        atomicAdd(&arow[f0 + 3],      w * bf2f(u0.w));
        atomicAdd(&arow[16 + f0 + 0], w * bf2f(u1.x));
        atomicAdd(&arow[16 + f0 + 1], w * bf2f(u1.y));
        atomicAdd(&arow[16 + f0 + 2], w * bf2f(u1.z));
        atomicAdd(&arow[16 + f0 + 3], w * bf2f(u1.w));
        atomicAdd(&arow[32 + f0 + 0], w * bf2f(u2.x));
        atomicAdd(&arow[32 + f0 + 1], w * bf2f(u2.y));
        atomicAdd(&arow[32 + f0 + 2], w * bf2f(u2.z));
        atomicAdd(&arow[32 + f0 + 3], w * bf2f(u2.w));
    }
    __syncthreads();
    int node0 = b << BKT_SHIFT;
    for (int rr = g; rr < BKT_NODES; rr += 128) {
        int node = node0 + rr;
        if (node >= N_NODES) break;
        const float* arow = acc + rr * ACC_STRIDE;
        float v0x = arow[f0+0],    v0y = arow[f0+1],    v0z = arow[f0+2],    v0w = arow[f0+3];
        float v1x = arow[16+f0+0], v1y = arow[16+f0+1], v1z = arow[16+f0+2], v1w = arow[16+f0+3];
        float v2x = arow[32+f0+0], v2y = arow[32+f0+1], v2z = arow[32+f0+2], v2w = arow[32+f0+3];
        if (OUT_BF16) {
            ushort4* orow = reinterpret_cast<ushort4*>((unsigned short*)outv + (size_t)node * D_FEAT);
            ushort4 o0, o1, o2;
            o0.x = bf16_rn(v0x); o0.y = bf16_rn(v0y); o0.z = bf16_rn(v0z); o0.w = bf16_rn(v0w);
            o1.x = bf16_rn(v1x); o1.y = bf16_rn(v1y); o1.z = bf16_rn(v1z); o1.w = bf16_rn(v1w);
            o2.x = bf16_rn(v2x); o2.y = bf16_rn(v2y); o2.z = bf16_rn(v2z); o2.w = bf16_rn(v2w);
            orow[q] = o0; orow[4 + q] = o1; orow[8 + q] = o2;
        } else {
            float4* orow = reinterpret_cast<float4*>((float*)outv + (size_t)node * D_FEAT);
            orow[q]     = make_float4(v0x, v0y, v0z, v0w);
            orow[4 + q] = make_float4(v1x, v1y, v1z, v1w);
            orow[8 + q] = make_float4(v2x, v2y, v2z, v2w);
        }
    }
}

extern "C" void kernel_launch(void* const* d_in, const int* in_sizes, int n_in,
                              void* d_out, int out_size, void* d_ws, size_t ws_size,
                              hipStream_t stream) {
    const float* x    = (const float*)d_in[0];
    const float* ew   = (const float*)d_in[1];
    const int*   esrc = (const int*)d_in[2];
    const int*   edst = (const int*)d_in[3];
    float* out = (float*)d_out;

    // Workspace layout. tmpb shares its slot with coarse (p2 consumes coarse
    // before spmm pass 1 writes tmpb).
    char* ws = (char*)d_ws;
    unsigned short* xb = (unsigned short*)ws;                 // 9.6 MB
    ws += (((size_t)N_NODES * D_FEAT * sizeof(unsigned short)) + 15) & ~15ull;
    unsigned short* tmpb = (unsigned short*)ws;
    uint2* coarse = (uint2*)ws;
    ws += (size_t)N_EDGES * sizeof(uint2);                    // 12.8 MB
    uint2* recs = (uint2*)ws;
    ws += (size_t)N_EDGES * sizeof(uint2);                    // 12.8 MB
    int* ccount = (int*)ws;
    ws += ((size_t)NBKT * sizeof(int) + 15) & ~15ull;
    int* bbase = (int*)ws;
    ws += ((size_t)(NBKT + 1) * sizeof(int) + 15) & ~15ull;
    int* cursor = (int*)ws;

    dim3 blk(256);

    // CSR build + bf16 conversion
    hipMemsetAsync(ccount, 0, NBKT * sizeof(int), stream);
    cvt_hist_kernel<<<1024, blk, 0, stream>>>(x, xb, edst, ccount);
    scan196_kernel<<<1, blk, 0, stream>>>(ccount, bbase, cursor);
    p1_kernel<<<NB1, blk, 0, stream>>>(ew, esrc, edst, cursor, coarse);
    p2_kernel<<<NBKT, dim3(512), 0, stream>>>(coarse, bbase, recs);

    // Pass 1: tmpb = bf16(A @ xb) ; Pass 2: out = A @ tmpb (f32 out)
    spmm_lds_kernel<true><<<NBKT, dim3(512), 0, stream>>>(xb, recs, bbase, tmpb);
    spmm_lds_kernel<false><<<NBKT, dim3(512), 0, stream>>>(tmpb, recs, bbase, out);
}

// Round 12
// 821.839 us; speedup vs baseline: 1.4490x; 1.4490x over previous
//
#include <hip/hip_runtime.h>

#define N_NODES 100000
#define N_EDGES 1600000
#define D_FEAT  48

#define BKT_SHIFT 9                                   // 512 nodes per coarse bucket
#define BKT_NODES (1 << BKT_SHIFT)
#define NBKT ((N_NODES + BKT_NODES - 1) / BKT_NODES)  // 196
#define EPB1 2048                                     // edges per phase-1 block
#define NB1  ((N_EDGES + EPB1 - 1) / EPB1)            // 782
#define P2_CAP 9216                                   // LDS-staged edges (avg 8192)
#define TILE_SHIFT 14                                 // src tile = src>>14
#define NTILE 8
#define KEYS (BKT_NODES * NTILE)                      // 4096
#define DEG_BINS 512

__device__ __forceinline__ unsigned short bf16_rn(float f) {
    unsigned u = __float_as_uint(f);
    unsigned r = (u + 0x7fffu + ((u >> 16) & 1u)) >> 16;
    return (unsigned short)r;
}
__device__ __forceinline__ float bf2f(unsigned short b) {
    return __uint_as_float(((unsigned)b) << 16);
}

// ---------- fused: x(f32)->xb(bf16)  +  coarse histogram ----------
__global__ void cvt_hist_kernel(const float* __restrict__ in,
                                unsigned short* __restrict__ outb,
                                const int* __restrict__ dst,
                                int* __restrict__ ccount) {
    __shared__ int cnt[NBKT];
    for (int i = threadIdx.x; i < NBKT; i += blockDim.x) cnt[i] = 0;
    __syncthreads();
    int tid = blockIdx.x * blockDim.x + threadIdx.x;
    int stride = gridDim.x * blockDim.x;
    const float4* in4 = (const float4*)in;
    ushort4* o4 = (ushort4*)outb;
    const int n4 = (N_NODES * D_FEAT) / 4;
    for (int i = tid; i < n4; i += stride) {
        float4 v = in4[i];
        ushort4 o;
        o.x = bf16_rn(v.x); o.y = bf16_rn(v.y);
        o.z = bf16_rn(v.z); o.w = bf16_rn(v.w);
        o4[i] = o;
    }
    for (int e = tid; e < N_EDGES; e += stride)
        atomicAdd(&cnt[dst[e] >> BKT_SHIFT], 1);
    __syncthreads();
    for (int i = threadIdx.x; i < NBKT; i += blockDim.x)
        if (cnt[i]) atomicAdd(&ccount[i], cnt[i]);
}

__global__ void scan196_kernel(const int* __restrict__ ccount,
                               int* __restrict__ bbase,
                               int* __restrict__ cursor,
                               int* __restrict__ row_ptr) {
    __shared__ int sdata[256];
    int t = threadIdx.x;
    int v = (t < NBKT) ? ccount[t] : 0;
    sdata[t] = v;
    __syncthreads();
    for (int off = 1; off < 256; off <<= 1) {
        int u = (t >= off) ? sdata[t - off] : 0;
        __syncthreads();
        sdata[t] += u;
        __syncthreads();
    }
    if (t < NBKT) { int ex = sdata[t] - v; bbase[t] = ex; cursor[t] = ex; }
    if (t == 0)   { bbase[NBKT] = N_EDGES; row_ptr[N_NODES] = N_EDGES; }
}

// coarse.x = dst_local(9b) | src<<9 ; coarse.y = w bits.
__global__ void p1_kernel(const float* __restrict__ w,
                          const int*   __restrict__ src,
                          const int*   __restrict__ dst,
                          int*         __restrict__ cursor,
                          uint2*       __restrict__ coarse) {
    __shared__ uint2 stage[EPB1];
    __shared__ unsigned char sbkt[EPB1];
    __shared__ int cnt[NBKT], base[NBKT];
    for (int i = threadIdx.x; i < NBKT; i += blockDim.x) cnt[i] = 0;
    __syncthreads();
    int e0 = blockIdx.x * EPB1;
    int n = N_EDGES - e0; if (n > EPB1) n = EPB1;
    for (int i = threadIdx.x; i < n; i += blockDim.x) {
        int e = e0 + i;
        int d = dst[e];
        int b = d >> BKT_SHIFT;
        atomicAdd(&cnt[b], 1);
        stage[i] = make_uint2((unsigned)(d & (BKT_NODES - 1)) | ((unsigned)src[e] << BKT_SHIFT),
                              (unsigned)__float_as_uint(w[e]));
        sbkt[i] = (unsigned char)b;
    }
    __syncthreads();
    for (int i = threadIdx.x; i < NBKT; i += blockDim.x) {
        int c = cnt[i];
        base[i] = c ? atomicAdd(&cursor[i], c) : 0;
        cnt[i] = 0;  // reuse as local cursor
    }
    __syncthreads();
    for (int i = threadIdx.x; i < n; i += blockDim.x) {
        int b = sbkt[i];
        int pos = base[b] + atomicAdd(&cnt[b], 1);
        coarse[pos] = stage[i];
    }
}

// Phase 2: one block per coarse bucket; key = dst_local*8 + src_tile.
// Thread t owns node (b<<9)+t -> writes row_ptr; also feeds the degree hist.
__global__ __launch_bounds__(512) void p2_kernel(const uint2* __restrict__ coarse,
                                                 const int*   __restrict__ bbase,
                                                 int2*        __restrict__ recs,
                                                 int*         __restrict__ row_ptr,
                                                 int*         __restrict__ dbin) {
    __shared__ uint2 sedge[P2_CAP];     // 72 KB
    __shared__ int cnt[KEYS];           // 16 KB
    __shared__ int ssum[512];           // 2 KB
    int b = blockIdx.x, t = threadIdx.x;
    int lo = bbase[b], hi = bbase[b + 1];
    int m = hi - lo;
    int staged = (m < P2_CAP) ? m : P2_CAP;
    for (int i = t; i < staged; i += 512) sedge[i] = coarse[lo + i];
    for (int k = t; k < KEYS; k += 512) cnt[k] = 0;
    __syncthreads();
    for (int i = t; i < m; i += 512) {
        uint2 r = (i < staged) ? sedge[i] : coarse[lo + i];
        unsigned key = ((r.x & (BKT_NODES - 1)) << 3) | ((r.x >> BKT_SHIFT) >> TILE_SHIFT);
        atomicAdd(&cnt[key], 1);
    }
    __syncthreads();
    int base = t << 3;
    int local[NTILE];
    int s = 0;
#pragma unroll
    for (int j = 0; j < NTILE; ++j) { local[j] = s; s += cnt[base + j]; }
    ssum[t] = s;
    __syncthreads();
    for (int off = 1; off < 512; off <<= 1) {
        int u = (t >= off) ? ssum[t - off] : 0;
        __syncthreads();
        ssum[t] += u;
        __syncthreads();
    }
    int pre = lo + ssum[t] - s;          // global start of this node's edges
    int node = (b << BKT_SHIFT) + t;
    if (node < N_NODES) {
        row_ptr[node] = pre;
        int d = (s < DEG_BINS) ? s : (DEG_BINS - 1);
        atomicAdd(&dbin[d], 1);          // degree histogram (for wave balancing)
    }
#pragma unroll
    for (int j = 0; j < NTILE; ++j) cnt[base + j] = pre + local[j];
    __syncthreads();
    for (int i = t; i < m; i += 512) {
        uint2 r = (i < staged) ? sedge[i] : coarse[lo + i];
        unsigned src = r.x >> BKT_SHIFT;
        unsigned key = ((r.x & (BKT_NODES - 1)) << 3) | (src >> TILE_SHIFT);
        int pos = atomicAdd(&cnt[key], 1);
        recs[pos] = make_int2((int)src, (int)r.y);
    }
}

// Reverse (descending-degree) exclusive scan of the 512 degree bins.
__global__ __launch_bounds__(512) void dscan_kernel(const int* __restrict__ dbin,
                                                    int* __restrict__ dcur) {
    __shared__ int sdata[DEG_BINS];
    int t = threadIdx.x;
    int d = DEG_BINS - 1 - t;            // process bins high->low
    int c = dbin[d];
    sdata[t] = c;
    __syncthreads();
    for (int off = 1; off < DEG_BINS; off <<= 1) {
        int u = (t >= off) ? sdata[t - off] : 0;
        __syncthreads();
        sdata[t] += u;
        __syncthreads();
    }
    dcur[d] = sdata[t] - c;              // base = count of nodes with larger degree
}

// order[pos] = node, descending degree (ties arbitrary).
__global__ void dscatter_kernel(const int* __restrict__ row_ptr,
                                int* __restrict__ dcur,
                                int* __restrict__ order) {
    int n = blockIdx.x * blockDim.x + threadIdx.x;
    if (n >= N_NODES) return;
    int deg = row_ptr[n + 1] - row_ptr[n];
    if (deg > DEG_BINS - 1) deg = DEG_BINS - 1;
    int pos = atomicAdd(&dcur[deg], 1);
    order[pos] = n;
}

// ---------- SpMM gather (bf16, f32 acc, unroll 4, degree-balanced waves) ----------
__device__ __forceinline__ void acc4(float* a, ushort4 u, float w) {
    a[0] += w * bf2f(u.x);
    a[1] += w * bf2f(u.y);
    a[2] += w * bf2f(u.z);
    a[3] += w * bf2f(u.w);
}

template <bool OUT_BF16>
__global__ void spmm_gather_b_kernel(const unsigned short* __restrict__ xb,
                                     const int2* __restrict__ recs,
                                     const int*  __restrict__ row_ptr,
                                     const int*  __restrict__ order,
                                     void* __restrict__ outv) {
    int tid = blockIdx.x * blockDim.x + threadIdx.x;
    int idx = tid >> 2;
    int l = tid & 3;
    if (idx >= N_NODES) return;
    int n = order[idx];                  // wave's 16 nodes have ~equal degree
    int e   = row_ptr[n];
    int end = row_ptr[n + 1];
    float a0[4] = {0.f, 0.f, 0.f, 0.f};
    float a1[4] = {0.f, 0.f, 0.f, 0.f};
    float a2[4] = {0.f, 0.f, 0.f, 0.f};
    const ushort4* __restrict__ X = reinterpret_cast<const ushort4*>(xb);
    for (; e + 3 < end; e += 4) {
        int2 r0 = recs[e],     r1 = recs[e + 1];
        int2 r2 = recs[e + 2], r3 = recs[e + 3];
        const ushort4* x0 = X + (size_t)r0.x * (D_FEAT / 4);
        const ushort4* x1 = X + (size_t)r1.x * (D_FEAT / 4);
        const ushort4* x2 = X + (size_t)r2.x * (D_FEAT / 4);
        const ushort4* x3 = X + (size_t)r3.x * (D_FEAT / 4);
        ushort4 u00 = x0[l], u01 = x0[4 + l], u02 = x0[8 + l];
        ushort4 u10 = x1[l], u11 = x1[4 + l], u12 = x1[8 + l];
        ushort4 u20 = x2[l], u21 = x2[4 + l], u22 = x2[8 + l];
        ushort4 u30 = x3[l], u31 = x3[4 + l], u32 = x3[8 + l];
        float w0 = __int_as_float(r0.y), w1 = __int_as_float(r1.y);
        float w2 = __int_as_float(r2.y), w3 = __int_as_float(r3.y);
        acc4(a0, u00, w0); acc4(a1, u01, w0); acc4(a2, u02, w0);
        acc4(a0, u10, w1); acc4(a1, u11, w1); acc4(a2, u12, w1);
        acc4(a0, u20, w2); acc4(a1, u21, w2); acc4(a2, u22, w2);
        acc4(a0, u30, w3); acc4(a1, u31, w3); acc4(a2, u32, w3);
    }
    for (; e < end; ++e) {
        int2 r = recs[e];
        float we = __int_as_float(r.y);
        const ushort4* xr = X + (size_t)r.x * (D_FEAT / 4);
        acc4(a0, xr[l], we); acc4(a1, xr[4 + l], we); acc4(a2, xr[8 + l], we);
    }
    if (OUT_BF16) {
        ushort4* orow = reinterpret_cast<ushort4*>((unsigned short*)outv + (size_t)n * D_FEAT);
        ushort4 o0, o1, o2;
        o0.x = bf16_rn(a0[0]); o0.y = bf16_rn(a0[1]); o0.z = bf16_rn(a0[2]); o0.w = bf16_rn(a0[3]);
        o1.x = bf16_rn(a1[0]); o1.y = bf16_rn(a1[1]); o1.z = bf16_rn(a1[2]); o1.w = bf16_rn(a1[3]);
        o2.x = bf16_rn(a2[0]); o2.y = bf16_rn(a2[1]); o2.z = bf16_rn(a2[2]); o2.w = bf16_rn(a2[3]);
        orow[l] = o0; orow[4 + l] = o1; orow[8 + l] = o2;
    } else {
        float4* orow = reinterpret_cast<float4*>((float*)outv + (size_t)n * D_FEAT);
        orow[l]     = make_float4(a0[0], a0[1], a0[2], a0[3]);
        orow[4 + l] = make_float4(a1[0], a1[1], a1[2], a1[3]);
        orow[8 + l] = make_float4(a2[0], a2[1], a2[2], a2[3]);
    }
}

extern "C" void kernel_launch(void* const* d_in, const int* in_sizes, int n_in,
                              void* d_out, int out_size, void* d_ws, size_t ws_size,
                              hipStream_t stream) {
    const float* x    = (const float*)d_in[0];
    const float* ew   = (const float*)d_in[1];
    const int*   esrc = (const int*)d_in[2];
    const int*   edst = (const int*)d_in[3];
    float* out = (float*)d_out;

    // Workspace layout. tmpb shares its slot with coarse (p2 consumes coarse
    // before spmm pass 1 writes tmpb).
    char* ws = (char*)d_ws;
    unsigned short* xb = (unsigned short*)ws;                 // 9.6 MB
    ws += (((size_t)N_NODES * D_FEAT * sizeof(unsigned short)) + 15) & ~15ull;
    unsigned short* tmpb = (unsigned short*)ws;
    uint2* coarse = (uint2*)ws;
    ws += (size_t)N_EDGES * sizeof(uint2);                    // 12.8 MB
    int2* recs = (int2*)ws;
    ws += (size_t)N_EDGES * sizeof(int2);                     // 12.8 MB
    int* row_ptr = (int*)ws;
    ws += ((size_t)(N_NODES + 1) * sizeof(int) + 15) & ~15ull;
    int* order = (int*)ws;                                    // 400 KB
    ws += ((size_t)N_NODES * sizeof(int) + 15) & ~15ull;
    int* ccount = (int*)ws;                                   // 256 ints (padded)
    ws += 256 * sizeof(int);
    int* dbin = (int*)ws;                                     // 512 ints
    ws += DEG_BINS * sizeof(int);
    int* dcur = (int*)ws;
    ws += DEG_BINS * sizeof(int);
    int* bbase = (int*)ws;
    ws += ((size_t)(NBKT + 1) * sizeof(int) + 15) & ~15ull;
    int* cursor = (int*)ws;

    dim3 blk(256);
    dim3 grid_nodes(((size_t)N_NODES * 4 + 255) / 256);

    // CSR build + bf16 conversion + degree-balanced order
    hipMemsetAsync(ccount, 0, (256 + DEG_BINS) * sizeof(int), stream);  // ccount + dbin
    cvt_hist_kernel<<<1024, blk, 0, stream>>>(x, xb, edst, ccount);
    scan196_kernel<<<1, blk, 0, stream>>>(ccount, bbase, cursor, row_ptr);
    p1_kernel<<<NB1, blk, 0, stream>>>(ew, esrc, edst, cursor, coarse);
    p2_kernel<<<NBKT, dim3(512), 0, stream>>>(coarse, bbase, recs, row_ptr, dbin);
    dscan_kernel<<<1, dim3(512), 0, stream>>>(dbin, dcur);
    dscatter_kernel<<<(N_NODES + 255) / 256, blk, 0, stream>>>(row_ptr, dcur, order);

    // Pass 1: tmpb = bf16(A @ xb) ; Pass 2: out = A @ tmpb (f32 out)
    spmm_gather_b_kernel<true><<<grid_nodes, blk, 0, stream>>>(xb, recs, row_ptr, order, tmpb);
    spmm_gather_b_kernel<false><<<grid_nodes, blk, 0, stream>>>(tmpb, recs, row_ptr, order, out);
}

// Round 13
// 228.389 us; speedup vs baseline: 5.2139x; 3.5984x over previous
//
#include <hip/hip_runtime.h>

#define N_NODES 100000
#define N_EDGES 1600000
#define D_FEAT  48

#define BKT_SHIFT 9                                   // 512 nodes per coarse bucket
#define BKT_NODES (1 << BKT_SHIFT)
#define NBKT ((N_NODES + BKT_NODES - 1) / BKT_NODES)  // 196
#define EPB1 2048                                     // edges per phase-1 block
#define NB1  ((N_EDGES + EPB1 - 1) / EPB1)            // 782
#define TILE_SHIFT 14
#define NTILE 8
#define KEYS (BKT_NODES * NTILE)                      // 4096

__device__ __forceinline__ unsigned short bf16_rn(float f) {
    unsigned u = __float_as_uint(f);
    unsigned r = (u + 0x7fffu + ((u >> 16) & 1u)) >> 16;
    return (unsigned short)r;
}
__device__ __forceinline__ float bf2f(unsigned short b) {
    return __uint_as_float(((unsigned)b) << 16);
}

// ---------- fused: x(f32)->xb(bf16)  +  coarse histogram ----------
__global__ void cvt_hist_kernel(const float* __restrict__ in,
                                unsigned short* __restrict__ outb,
                                const int* __restrict__ dst,
                                int* __restrict__ ccount) {
    __shared__ int cnt[NBKT];
    for (int i = threadIdx.x; i < NBKT; i += blockDim.x) cnt[i] = 0;
    __syncthreads();
    int tid = blockIdx.x * blockDim.x + threadIdx.x;
    int stride = gridDim.x * blockDim.x;
    const float4* in4 = (const float4*)in;
    ushort4* o4 = (ushort4*)outb;
    const int n4 = (N_NODES * D_FEAT) / 4;
    for (int i = tid; i < n4; i += stride) {
        float4 v = in4[i];
        ushort4 o;
        o.x = bf16_rn(v.x); o.y = bf16_rn(v.y);
        o.z = bf16_rn(v.z); o.w = bf16_rn(v.w);
        o4[i] = o;
    }
    for (int e = tid; e < N_EDGES; e += stride)
        atomicAdd(&cnt[dst[e] >> BKT_SHIFT], 1);
    __syncthreads();
    for (int i = threadIdx.x; i < NBKT; i += blockDim.x)
        if (cnt[i]) atomicAdd(&ccount[i], cnt[i]);
}

__global__ void scan196_kernel(const int* __restrict__ ccount,
                               int* __restrict__ bbase,
                               int* __restrict__ cursor,
                               int* __restrict__ row_ptr) {
    __shared__ int sdata[256];
    int t = threadIdx.x;
    int v = (t < NBKT) ? ccount[t] : 0;
    sdata[t] = v;
    __syncthreads();
    for (int off = 1; off < 256; off <<= 1) {
        int u = (t >= off) ? sdata[t - off] : 0;
        __syncthreads();
        sdata[t] += u;
        __syncthreads();
    }
    if (t < NBKT) { int ex = sdata[t] - v; bbase[t] = ex; cursor[t] = ex; }
    if (t == 0)   { bbase[NBKT] = N_EDGES; row_ptr[N_NODES] = N_EDGES; }
}

// coarse.x = dst_local(9b) | src<<9 ; coarse.y = w bits (f32).
__global__ void p1_kernel(const float* __restrict__ w,
                          const int*   __restrict__ src,
                          const int*   __restrict__ dst,
                          int*         __restrict__ cursor,
                          uint2*       __restrict__ coarse) {
    __shared__ uint2 stage[EPB1];
    __shared__ unsigned char sbkt[EPB1];
    __shared__ int cnt[NBKT], base[NBKT];
    for (int i = threadIdx.x; i < NBKT; i += blockDim.x) cnt[i] = 0;
    __syncthreads();
    int e0 = blockIdx.x * EPB1;
    int n = N_EDGES - e0; if (n > EPB1) n = EPB1;
    for (int i = threadIdx.x; i < n; i += blockDim.x) {
        int e = e0 + i;
        int d = dst[e];
        int b = d >> BKT_SHIFT;
        atomicAdd(&cnt[b], 1);
        stage[i] = make_uint2((unsigned)(d & (BKT_NODES - 1)) | ((unsigned)src[e] << BKT_SHIFT),
                              (unsigned)__float_as_uint(w[e]));
        sbkt[i] = (unsigned char)b;
    }
    __syncthreads();
    for (int i = threadIdx.x; i < NBKT; i += blockDim.x) {
        int c = cnt[i];
        base[i] = c ? atomicAdd(&cursor[i], c) : 0;
        cnt[i] = 0;  // reuse as local cursor
    }
    __syncthreads();
    for (int i = threadIdx.x; i < n; i += blockDim.x) {
        int b = sbkt[i];
        int pos = base[b] + atomicAdd(&cnt[b], 1);
        coarse[pos] = stage[i];
    }
}

// Phase 2: one block per coarse bucket; NO LDS edge staging (bucket is
// L2-resident, ~64KB) -> LDS 18KB -> 2+ blocks/CU. Key = dst_local*8+tile.
// recs packed to 4B: w15(bf16 sans sign)<<17 | src.
__global__ __launch_bounds__(512) void p2_kernel(const uint2* __restrict__ coarse,
                                                 const int*   __restrict__ bbase,
                                                 unsigned*    __restrict__ recs,
                                                 int*         __restrict__ row_ptr) {
    __shared__ int cnt[KEYS];           // 16 KB
    __shared__ int ssum[512];           // 2 KB
    int b = blockIdx.x, t = threadIdx.x;
    int lo = bbase[b], hi = bbase[b + 1];
    int m = hi - lo;
    for (int k = t; k < KEYS; k += 512) cnt[k] = 0;
    __syncthreads();
    for (int i = t; i < m; i += 512) {
        uint2 r = coarse[lo + i];
        unsigned key = ((r.x & (BKT_NODES - 1)) << 3) | ((r.x >> BKT_SHIFT) >> TILE_SHIFT);
        atomicAdd(&cnt[key], 1);
    }
    __syncthreads();
    int base = t << 3;                   // thread t owns node t's 8 tile-keys
    int local[NTILE];
    int s = 0;
#pragma unroll
    for (int j = 0; j < NTILE; ++j) { local[j] = s; s += cnt[base + j]; }
    ssum[t] = s;
    __syncthreads();
    for (int off = 1; off < 512; off <<= 1) {
        int u = (t >= off) ? ssum[t - off] : 0;
        __syncthreads();
        ssum[t] += u;
        __syncthreads();
    }
    int pre = lo + ssum[t] - s;          // global start of this node's edges
    int node = (b << BKT_SHIFT) + t;
    if (node < N_NODES) row_ptr[node] = pre;
#pragma unroll
    for (int j = 0; j < NTILE; ++j) cnt[base + j] = pre + local[j];
    __syncthreads();
    for (int i = t; i < m; i += 512) {
        uint2 r = coarse[lo + i];
        unsigned src = r.x >> BKT_SHIFT;
        unsigned key = ((r.x & (BKT_NODES - 1)) << 3) | (src >> TILE_SHIFT);
        int pos = atomicAdd(&cnt[key], 1);
        unsigned w15 = (unsigned)bf16_rn(__uint_as_float(r.y)) & 0x7FFFu;  // sign==0 (w>=0)
        recs[pos] = (w15 << 17) | src;
    }
}

// ---------- SpMM gather (bf16 features, f32 acc, 4B recs, unroll 4) ----------
__device__ __forceinline__ void acc4(float* a, ushort4 u, float w) {
    a[0] += w * bf2f(u.x);
    a[1] += w * bf2f(u.y);
    a[2] += w * bf2f(u.z);
    a[3] += w * bf2f(u.w);
}
__device__ __forceinline__ float rec_w(unsigned r) {
    return __uint_as_float((r >> 1) & 0xFFFF0000u);
}

template <bool OUT_BF16>
__global__ void spmm_gather_b_kernel(const unsigned short* __restrict__ xb,
                                     const unsigned* __restrict__ recs,
                                     const int*  __restrict__ row_ptr,
                                     void* __restrict__ outv) {
    int tid = blockIdx.x * blockDim.x + threadIdx.x;
    int n = tid >> 2;
    int l = tid & 3;
    if (n >= N_NODES) return;
    int e   = row_ptr[n];
    int end = row_ptr[n + 1];
    float a0[4] = {0.f, 0.f, 0.f, 0.f};
    float a1[4] = {0.f, 0.f, 0.f, 0.f};
    float a2[4] = {0.f, 0.f, 0.f, 0.f};
    const ushort4* __restrict__ X = reinterpret_cast<const ushort4*>(xb);
    for (; e + 3 < end; e += 4) {
        unsigned r0 = recs[e],     r1 = recs[e + 1];
        unsigned r2 = recs[e + 2], r3 = recs[e + 3];
        const ushort4* x0 = X + (size_t)(r0 & 0x1FFFFu) * (D_FEAT / 4);
        const ushort4* x1 = X + (size_t)(r1 & 0x1FFFFu) * (D_FEAT / 4);
        const ushort4* x2 = X + (size_t)(r2 & 0x1FFFFu) * (D_FEAT / 4);
        const ushort4* x3 = X + (size_t)(r3 & 0x1FFFFu) * (D_FEAT / 4);
        ushort4 u00 = x0[l], u01 = x0[4 + l], u02 = x0[8 + l];
        ushort4 u10 = x1[l], u11 = x1[4 + l], u12 = x1[8 + l];
        ushort4 u20 = x2[l], u21 = x2[4 + l], u22 = x2[8 + l];
        ushort4 u30 = x3[l], u31 = x3[4 + l], u32 = x3[8 + l];
        float w0 = rec_w(r0), w1 = rec_w(r1);
        float w2 = rec_w(r2), w3 = rec_w(r3);
        acc4(a0, u00, w0); acc4(a1, u01, w0); acc4(a2, u02, w0);
        acc4(a0, u10, w1); acc4(a1, u11, w1); acc4(a2, u12, w1);
        acc4(a0, u20, w2); acc4(a1, u21, w2); acc4(a2, u22, w2);
        acc4(a0, u30, w3); acc4(a1, u31, w3); acc4(a2, u32, w3);
    }
    for (; e < end; ++e) {
        unsigned r = recs[e];
        float we = rec_w(r);
        const ushort4* xr = X + (size_t)(r & 0x1FFFFu) * (D_FEAT / 4);
        acc4(a0, xr[l], we); acc4(a1, xr[4 + l], we); acc4(a2, xr[8 + l], we);
    }
    if (OUT_BF16) {
        ushort4* orow = reinterpret_cast<ushort4*>((unsigned short*)outv + (size_t)n * D_FEAT);
        ushort4 o0, o1, o2;
        o0.x = bf16_rn(a0[0]); o0.y = bf16_rn(a0[1]); o0.z = bf16_rn(a0[2]); o0.w = bf16_rn(a0[3]);
        o1.x = bf16_rn(a1[0]); o1.y = bf16_rn(a1[1]); o1.z = bf16_rn(a1[2]); o1.w = bf16_rn(a1[3]);
        o2.x = bf16_rn(a2[0]); o2.y = bf16_rn(a2[1]); o2.z = bf16_rn(a2[2]); o2.w = bf16_rn(a2[3]);
        orow[l] = o0; orow[4 + l] = o1; orow[8 + l] = o2;
    } else {
        float4* orow = reinterpret_cast<float4*>((float*)outv + (size_t)n * D_FEAT);
        orow[l]     = make_float4(a0[0], a0[1], a0[2], a0[3]);
        orow[4 + l] = make_float4(a1[0], a1[1], a1[2], a1[3]);
        orow[8 + l] = make_float4(a2[0], a2[1], a2[2], a2[3]);
    }
}

extern "C" void kernel_launch(void* const* d_in, const int* in_sizes, int n_in,
                              void* d_out, int out_size, void* d_ws, size_t ws_size,
                              hipStream_t stream) {
    const float* x    = (const float*)d_in[0];
    const float* ew   = (const float*)d_in[1];
    const int*   esrc = (const int*)d_in[2];
    const int*   edst = (const int*)d_in[3];
    float* out = (float*)d_out;

    // Workspace layout. tmpb shares its slot with coarse (p2 consumes coarse
    // before spmm pass 1 writes tmpb).
    char* ws = (char*)d_ws;
    unsigned short* xb = (unsigned short*)ws;                 // 9.6 MB
    ws += (((size_t)N_NODES * D_FEAT * sizeof(unsigned short)) + 15) & ~15ull;
    unsigned short* tmpb = (unsigned short*)ws;
    uint2* coarse = (uint2*)ws;
    ws += (size_t)N_EDGES * sizeof(uint2);                    // 12.8 MB
    unsigned* recs = (unsigned*)ws;
    ws += (size_t)N_EDGES * sizeof(unsigned);                 // 6.4 MB
    int* row_ptr = (int*)ws;
    ws += ((size_t)(N_NODES + 1) * sizeof(int) + 15) & ~15ull;
    int* ccount = (int*)ws;
    ws += ((size_t)NBKT * sizeof(int) + 15) & ~15ull;
    int* bbase = (int*)ws;
    ws += ((size_t)(NBKT + 1) * sizeof(int) + 15) & ~15ull;
    int* cursor = (int*)ws;

    dim3 blk(256);
    dim3 grid_nodes(((size_t)N_NODES * 4 + 255) / 256);

    // CSR build + bf16 conversion
    hipMemsetAsync(ccount, 0, NBKT * sizeof(int), stream);
    cvt_hist_kernel<<<1024, blk, 0, stream>>>(x, xb, edst, ccount);
    scan196_kernel<<<1, blk, 0, stream>>>(ccount, bbase, cursor, row_ptr);
    p1_kernel<<<NB1, blk, 0, stream>>>(ew, esrc, edst, cursor, coarse);
    p2_kernel<<<NBKT, dim3(512), 0, stream>>>(coarse, bbase, recs, row_ptr);

    // Pass 1: tmpb = bf16(A @ xb) ; Pass 2: out = A @ tmpb (f32 out)
    spmm_gather_b_kernel<true><<<grid_nodes, blk, 0, stream>>>(xb, recs, row_ptr, tmpb);
    spmm_gather_b_kernel<false><<<grid_nodes, blk, 0, stream>>>(tmpb, recs, row_ptr, out);
}